// Round 5
// baseline (869.009 us; speedup 1.0000x reference)
//
#include <hip/hip_runtime.h>

#define N_NODES 100000
#define N_EDGES 3200000
#define D 128
#define K 8

// |score32| below this => exact fp64 repair. fp32 score error sigma ~1e-5,
// so 2e-3 is ~200 sigma: no sign flip can survive unflagged.
#define TAU 2e-3f
#define WL_CAP 262144  // repair worklist capacity

#define CHUNK 64   // nodes per head_gemm block
#define CCH   32   // output columns per wave

// ---------------------------------------------------------------------------
// Phase 0: per-head compaction of masked node ids + per-node mask bitmap.
// lists[k][0..cnts[k]) = node ids with mask[n,k] > 0 (order ~ascending).
// mb[n] = bitmap of masked heads (gates scatter atomics + edge_flag).
// ---------------------------------------------------------------------------
__global__ __launch_bounds__(256)
void compact_kernel(const float* __restrict__ mask,
                    int* __restrict__ lists,
                    int* __restrict__ cnts,
                    unsigned char* __restrict__ mb)
{
    const int n = blockIdx.x * 256 + threadIdx.x;
    const int lane = threadIdx.x & 63;
    const bool valid = (n < N_NODES);
    int bits8 = 0;
    #pragma unroll
    for (int k = 0; k < K; ++k) {
        const bool m = valid && (mask[(size_t)n * K + k] > 0.0f);
        bits8 |= m ? (1 << k) : 0;
        const unsigned long long b = __ballot(m);
        const int cw = __popcll(b);
        int base = 0;
        if (lane == 0 && cw) base = atomicAdd(&cnts[k], cw);
        base = __shfl(base, 0);
        if (m) {
            const int pos = __popcll(b & ((1ull << lane) - 1ull));
            lists[(size_t)k * N_NODES + base + pos] = n;
        }
    }
    if (valid) mb[n] = (unsigned char)bits8;
}

// ---------------------------------------------------------------------------
// Phase 1 (fp32): for each compacted (node,head):
//   t32[n,k]    = relu(x[n] @ Ww_k) . Wm_k
//   base32[n,k] = x[n] . Wm_k
// Block = 64 nodes x 1 head; xT transposed in LDS (33 KB -> 4 blocks/CU).
// Lane = node; wave w owns cols [32w,32w+32): per j one conflict-free
// ds_read_b32 + 32 s-operand fmacs; W row j+1 software-prefetched (SGPRs)
// while row j is consumed, covering SMEM latency.
// Grid swizzle: bid = c0*64 + h*8 + clo (c = c0*8+clo) -> the 8 heads of a
// node-chunk share bid%8 (same XCD) and are adjacent in dispatch -> x rows
// reused out of that XCD's L2.
// ---------------------------------------------------------------------------
__global__ __launch_bounds__(256)
void head_gemm_kernel(const float* __restrict__ x,
                      const float* __restrict__ Ww,
                      const float* __restrict__ Wm,
                      const int* __restrict__ lists,
                      const int* __restrict__ cnts,
                      float* __restrict__ t32,
                      float* __restrict__ base32)
{
    __shared__ float xT[D][CHUNK + 1];   // 33.3 KB
    __shared__ float redT[4][CHUNK];
    __shared__ float redB[4][CHUNK];

    const int bid = blockIdx.x;
    const int k = (bid >> 3) & 7;
    const int c = ((bid >> 6) << 3) | (bid & 7);

    const int cnt = cnts[k];
    const int nbase = c * CHUNK;
    if (nbase >= cnt) return;            // block-uniform exit (before barriers)

    const int lane = threadIdx.x & 63;
    const int wave = __builtin_amdgcn_readfirstlane((int)(threadIdx.x >> 6));
    const int* list = lists + (size_t)k * N_NODES;

    // stage 16 rows per wave, transposed; clamp tail (duplicate rows harmless)
    #pragma unroll
    for (int i = 0; i < 16; ++i) {
        const int r = wave * 16 + i;
        int idx = nbase + r;
        if (idx >= cnt) idx = cnt - 1;
        const int id = __builtin_amdgcn_readfirstlane(list[idx]);
        xT[lane][r]      = x[(size_t)id * D + lane];        // 256 B coalesced
        xT[lane + 64][r] = x[(size_t)id * D + lane + 64];
    }
    __syncthreads();

    const int c0 = wave * CCH;
    const float* Wk = Ww + (size_t)k * D * D + c0;

    float acc[CCH];
    #pragma unroll
    for (int cc = 0; cc < CCH; ++cc) acc[cc] = 0.0f;

    // software-pipelined W row (wave-uniform -> SGPRs)
    float wbuf[CCH];
    #pragma unroll
    for (int cc = 0; cc < CCH; ++cc) wbuf[cc] = Wk[cc];

    #pragma unroll 2
    for (int j = 0; j < D; ++j) {
        float wnext[CCH];
        const float* wn = Wk + ((j + 1) & (D - 1)) * D;
        #pragma unroll
        for (int cc = 0; cc < CCH; ++cc) wnext[cc] = wn[cc];

        const float xv = xT[j][lane];          // conflict-free ds_read_b32
        #pragma unroll
        for (int cc = 0; cc < CCH; ++cc)
            acc[cc] = fmaf(xv, wbuf[cc], acc[cc]);  // v_fmac_f32 v, s, v

        #pragma unroll
        for (int cc = 0; cc < CCH; ++cc) wbuf[cc] = wnext[cc];
    }

    // epilogue: per-lane partials for this column chunk
    float tp = 0.0f, bp = 0.0f;
    #pragma unroll 4
    for (int cc = 0; cc < CCH; ++cc) {
        const float wm = Wm[k * D + c0 + cc];   // wave-uniform s_load
        tp = fmaf(fmaxf(acc[cc], 0.0f), wm, tp);
        bp = fmaf(xT[c0 + cc][lane], wm, bp);
    }
    redT[wave][lane] = tp;
    redB[wave][lane] = bp;
    __syncthreads();

    if (wave == 0) {
        const int idx = nbase + lane;
        if (idx < cnt) {
            const int id = list[idx];
            t32[(size_t)id * K + k]    = redT[0][lane] + redT[1][lane] +
                                         redT[2][lane] + redT[3][lane];
            base32[(size_t)id * K + k] = redB[0][lane] + redB[1][lane] +
                                         redB[2][lane] + redB[3][lane];
        }
    }
}

// ---------------------------------------------------------------------------
// Phase 2 (fp32): agg32[dst,k] += t32[src,k]. Thread per edge: vector t-row
// read; atomics gated by BOTH t!=0 (src masked & nonzero) and mb[dst] bit
// (agg is dead where dst unmasked) -> ~6.4M atomics instead of 12.8M.
// ---------------------------------------------------------------------------
__global__ __launch_bounds__(256)
void scatter_kernel(const int* __restrict__ ei,
                    const unsigned char* __restrict__ mb,
                    const float* __restrict__ t32,
                    float* __restrict__ agg32)
{
    const int e = blockIdx.x * 256 + threadIdx.x;
    if (e >= N_EDGES) return;
    const int d = ei[(long long)N_EDGES + e];
    const unsigned md = mb[d];
    if (!md) return;
    const int s = ei[e];
    const float4* tr = (const float4*)(t32 + (size_t)s * K);
    const float4 lo = tr[0];
    const float4 hi = tr[1];
    const float tv[K] = {lo.x, lo.y, lo.z, lo.w, hi.x, hi.y, hi.z, hi.w};
    float* ar = agg32 + (size_t)d * K;
    #pragma unroll
    for (int k = 0; k < K; ++k) {
        if (((md >> k) & 1) && tv[k] != 0.0f) atomicAdd(&ar[k], tv[k]);
    }
}

// ---------------------------------------------------------------------------
// Phase 3: tentative combine + flag near-zero scores for exact repair.
// head bool = (mask>0) && (score>0); output = first <=2 true heads (lax.top_k
// on all-equal norms tie-breaks by lowest index).
// ---------------------------------------------------------------------------
__global__ __launch_bounds__(256)
void combine_flag_kernel(const unsigned char* __restrict__ mb,
                         const float* __restrict__ base32,
                         const float* __restrict__ agg32,
                         float* __restrict__ out,
                         unsigned char* __restrict__ flag8)
{
    const int n = blockIdx.x * 256 + threadIdx.x;
    if (n >= N_NODES) return;
    const unsigned m8 = mb[n];
    float o[K];
    int cnt = 0, fl = 0;
    #pragma unroll
    for (int k = 0; k < K; ++k) {
        const float s = base32[(size_t)n * K + k] + agg32[(size_t)n * K + k];
        const bool masked = (m8 >> k) & 1;
        const bool hm = masked && (s > 0.0f);
        if (masked && fabsf(s) < TAU) fl |= (1 << k);
        o[k] = (hm && cnt < 2) ? 1.0f : 0.0f;
        cnt += hm ? 1 : 0;
    }
    float4* op = (float4*)(out + (size_t)n * K);
    op[0] = make_float4(o[0], o[1], o[2], o[3]);
    op[1] = make_float4(o[4], o[5], o[6], o[7]);
    flag8[n] = (unsigned char)fl;
}

// ---------------------------------------------------------------------------
// Repair A: edges into flagged (dst,k) with masked src -> worklist.
// ---------------------------------------------------------------------------
__global__ __launch_bounds__(256)
void edge_flag_kernel(const int* __restrict__ ei,
                      const unsigned char* __restrict__ mb,
                      const unsigned char* __restrict__ flag8,
                      int2* __restrict__ wl,
                      int* __restrict__ wlcnt)
{
    const int e = blockIdx.x * 256 + threadIdx.x;
    if (e >= N_EDGES) return;
    const int d = ei[(long long)N_EDGES + e];
    unsigned f = flag8[d];
    if (!f) return;
    const int s = ei[e];
    f &= mb[s];
    while (f) {
        const int k = __ffs(f) - 1;
        f &= f - 1;
        const int idx = atomicAdd(wlcnt, 1);
        if (idx < WL_CAP) wl[idx] = make_int2(s | (k << 20), d);
    }
}

// ---------------------------------------------------------------------------
// Repair B: one wave per worklist entry: exact fp64 t, atomic into score64.
// ---------------------------------------------------------------------------
__global__ __launch_bounds__(256)
void repair_t_kernel(const float* __restrict__ x,
                     const float* __restrict__ Ww,
                     const float* __restrict__ Wm,
                     const int2* __restrict__ wl,
                     const int* __restrict__ wlcnt,
                     double* __restrict__ score64)
{
    const int lane = threadIdx.x & 63;
    const int waveId = blockIdx.x * 4 + (threadIdx.x >> 6);
    const int nWaves = gridDim.x * 4;
    int cnt = *wlcnt;
    if (cnt > WL_CAP) cnt = WL_CAP;
    for (int w = waveId; w < cnt; w += nWaves) {
        const int2 ent = wl[w];
        const int s = __builtin_amdgcn_readfirstlane(ent.x & 0xFFFFF);
        const int k = __builtin_amdgcn_readfirstlane(ent.x >> 20);
        const int d = ent.y;
        const float* xr = x + (size_t)s * D;
        const float* Wk = Ww + (size_t)k * D * D;
        double c0 = 0.0, c1 = 0.0;
        for (int j = 0; j < D; ++j) {
            const double xd = (double)xr[j];
            c0 = fma(xd, (double)Wk[j * D + lane], c0);
            c1 = fma(xd, (double)Wk[j * D + lane + 64], c1);
        }
        double ts = fmax(c0, 0.0) * (double)Wm[k * D + lane]
                  + fmax(c1, 0.0) * (double)Wm[k * D + lane + 64];
        #pragma unroll
        for (int off = 32; off > 0; off >>= 1) ts += __shfl_xor(ts, off);
        if (lane == 0) atomicAdd(&score64[(size_t)d * K + k], ts);
    }
}

// ---------------------------------------------------------------------------
// Repair C: rewrite output rows of flagged nodes using exact scores.
// ---------------------------------------------------------------------------
__global__ __launch_bounds__(256)
void repair_combine_kernel(const float* __restrict__ x,
                           const unsigned char* __restrict__ mb,
                           const float* __restrict__ Wm,
                           const float* __restrict__ base32,
                           const float* __restrict__ agg32,
                           const double* __restrict__ score64,
                           const unsigned char* __restrict__ flag8,
                           float* __restrict__ out)
{
    const int n = blockIdx.x * 256 + threadIdx.x;
    if (n >= N_NODES) return;
    const unsigned f = flag8[n];
    if (!f) return;
    const unsigned m8 = mb[n];
    float o[K];
    int cnt = 0;
    #pragma unroll
    for (int k = 0; k < K; ++k) {
        bool hm;
        if ((f >> k) & 1) {
            double b = 0.0;
            for (int j = 0; j < D; ++j)
                b = fma((double)x[(size_t)n * D + j], (double)Wm[k * D + j], b);
            hm = (b + score64[(size_t)n * K + k]) > 0.0;
        } else {
            hm = ((m8 >> k) & 1) &&
                 ((base32[(size_t)n * K + k] + agg32[(size_t)n * K + k]) > 0.0f);
        }
        o[k] = (hm && cnt < 2) ? 1.0f : 0.0f;
        cnt += hm ? 1 : 0;
    }
    float4* op = (float4*)(out + (size_t)n * K);
    op[0] = make_float4(o[0], o[1], o[2], o[3]);
    op[1] = make_float4(o[4], o[5], o[6], o[7]);
}

extern "C" void kernel_launch(void* const* d_in, const int* in_sizes, int n_in,
                              void* d_out, int out_size, void* d_ws, size_t ws_size,
                              hipStream_t stream)
{
    const float* x    = (const float*)d_in[0];
    const int*   ei   = (const int*)d_in[1];   // edge_index [2, E] int32
    const float* mask = (const float*)d_in[2]; // [N, K]
    const float* Ww   = (const float*)d_in[3]; // [K, D, D]
    const float* Wm   = (const float*)d_in[4]; // [K, D, 1]
    float* out = (float*)d_out;                // [N, K] float32

    // workspace layout:
    //   [0, 3.2M)            t32      f32[N*K]
    //   [3.2M, 6.4M)         agg32    f32[N*K]
    //   [6.4M, 12.8M)        s64      f64[N*K]  (early: lists int[K][N], 3.2M)
    //   [12.8M, +100000)     flag8    u8[N]
    //   [12,900,000, +32)    cnts     int[8]
    //   [12,900,032, +4+pad) wlcnt    int
    //   [12,900,040, +2M)    wl       int2[WL_CAP]
    //   [14,997,192, +3.2M)  base32   f32[N*K]
    //   [18,197,192, +100000) mb      u8[N]      (end ~18.3 MB)
    char* w = (char*)d_ws;
    float*         t32    = (float*)w;
    float*         agg32  = (float*)(w + 3200000);
    double*        s64    = (double*)(w + 6400000);
    int*           lists  = (int*)(w + 6400000);       // overlays s64 (dead then)
    unsigned char* flag8  = (unsigned char*)(w + 12800000);
    int*           cnts   = (int*)(w + 12900000);
    int*           wlcnt  = (int*)(w + 12900032);
    int2*          wl     = (int2*)(w + 12900040);
    float*         b32    = (float*)(w + 12900040 + (size_t)WL_CAP * 8);
    unsigned char* mb     = (unsigned char*)(w + 12900040 + (size_t)WL_CAP * 8 + 3200000);

    // zero t32|agg32 and flag8|cnts|wlcnt (s64 zeroed later, after gemm)
    hipMemsetAsync(w, 0, 6400000, stream);
    hipMemsetAsync(w + 12800000, 0, 100040, stream);

    compact_kernel<<<(N_NODES + 255) / 256, 256, 0, stream>>>(mask, lists, cnts, mb);

    // grid: chunks padded to x8 so bid = c0*64 + h*8 + clo covers all (c,h)
    const int nchunks = (N_NODES + CHUNK - 1) / CHUNK;          // 1563
    const int nc8 = (nchunks + 7) & ~7;                          // 1568
    head_gemm_kernel<<<nc8 * K, 256, 0, stream>>>(x, Ww, Wm, lists, cnts, t32, b32);

    scatter_kernel<<<(N_EDGES + 255) / 256, 256, 0, stream>>>(ei, mb, t32, agg32);

    combine_flag_kernel<<<(N_NODES + 255) / 256, 256, 0, stream>>>(
        mb, b32, agg32, out, flag8);

    // lists dead now; zero s64 for exact re-accumulation
    hipMemsetAsync(s64, 0, 6400000, stream);

    edge_flag_kernel<<<(N_EDGES + 255) / 256, 256, 0, stream>>>(
        ei, mb, flag8, wl, wlcnt);

    repair_t_kernel<<<512, 256, 0, stream>>>(x, Ww, Wm, wl, wlcnt, s64);

    repair_combine_kernel<<<(N_NODES + 255) / 256, 256, 0, stream>>>(
        x, mb, Wm, b32, agg32, s64, flag8, out);
}

// Round 6
// 691.436 us; speedup vs baseline: 1.2568x; 1.2568x over previous
//
#include <hip/hip_runtime.h>

#define N_NODES 100000
#define N_EDGES 3200000
#define D 128
#define K 8

// |score32| below this => exact fp64 repair. fp32 score error sigma ~1e-5,
// so 2e-3 is ~200 sigma: no sign flip can survive unflagged.
#define TAU 2e-3f
#define WL_CAP 262144  // repair worklist capacity

#define CHUNK 64   // nodes per head_gemm block
#define CCH   32   // output columns per wave

// ---------------------------------------------------------------------------
// Phase 0: per-head compaction of masked node ids + per-node mask bitmap.
// ---------------------------------------------------------------------------
__global__ __launch_bounds__(256)
void compact_kernel(const float* __restrict__ mask,
                    int* __restrict__ lists,
                    int* __restrict__ cnts,
                    unsigned char* __restrict__ mb)
{
    const int n = blockIdx.x * 256 + threadIdx.x;
    const int lane = threadIdx.x & 63;
    const bool valid = (n < N_NODES);
    int bits8 = 0;
    #pragma unroll
    for (int k = 0; k < K; ++k) {
        const bool m = valid && (mask[(size_t)n * K + k] > 0.0f);
        bits8 |= m ? (1 << k) : 0;
        const unsigned long long b = __ballot(m);
        const int cw = __popcll(b);
        int base = 0;
        if (lane == 0 && cw) base = atomicAdd(&cnts[k], cw);
        base = __shfl(base, 0);
        if (m) {
            const int pos = __popcll(b & ((1ull << lane) - 1ull));
            lists[(size_t)k * N_NODES + base + pos] = n;
        }
    }
    if (valid) mb[n] = (unsigned char)bits8;
}

// ---------------------------------------------------------------------------
// Phase 1 (fp32): for each compacted (node,head):
//   t32[n,k]    = relu(x[n] @ Ww_k) . Wm_k
//   base32[n,k] = x[n] . Wm_k
// Block = 64 nodes x 1 head; xT transposed in LDS (33 KB -> 4 blocks/CU).
// Lane = node; wave w owns cols [32w,32w+32): per j one conflict-free
// ds_read_b32 + 32 s-operand fmacs (W row wave-uniform -> batched s_load;
// compiler's own scheduling beats a manual rotate pipeline — R5 post-mortem).
// Grid swizzle: bid = c0*64 + h*8 + clo -> the 8 heads of one node-chunk
// share bid%8 (same XCD), adjacent in dispatch -> x reused from that L2.
// ---------------------------------------------------------------------------
__global__ __launch_bounds__(256)
void head_gemm_kernel(const float* __restrict__ x,
                      const float* __restrict__ Ww,
                      const float* __restrict__ Wm,
                      const int* __restrict__ lists,
                      const int* __restrict__ cnts,
                      float* __restrict__ t32,
                      float* __restrict__ base32)
{
    __shared__ float xT[D][CHUNK + 1];   // 33.3 KB
    __shared__ float redT[4][CHUNK];
    __shared__ float redB[4][CHUNK];

    const int bid = blockIdx.x;
    const int k = (bid >> 3) & 7;
    const int c = ((bid >> 6) << 3) | (bid & 7);

    const int cnt = cnts[k];
    const int nbase = c * CHUNK;
    if (nbase >= cnt) return;            // block-uniform exit (before barriers)

    const int lane = threadIdx.x & 63;
    const int wave = __builtin_amdgcn_readfirstlane((int)(threadIdx.x >> 6));
    const int* list = lists + (size_t)k * N_NODES;

    // stage 16 rows per wave, transposed; clamp tail (duplicate rows harmless)
    #pragma unroll
    for (int i = 0; i < 16; ++i) {
        const int r = wave * 16 + i;
        int idx = nbase + r;
        if (idx >= cnt) idx = cnt - 1;
        const int id = __builtin_amdgcn_readfirstlane(list[idx]);
        xT[lane][r]      = x[(size_t)id * D + lane];        // 256 B coalesced
        xT[lane + 64][r] = x[(size_t)id * D + lane + 64];
    }
    __syncthreads();

    const int c0 = wave * CCH;
    const float* Wk = Ww + (size_t)k * D * D + c0;

    float acc[CCH];
    #pragma unroll
    for (int cc = 0; cc < CCH; ++cc) acc[cc] = 0.0f;

    #pragma unroll 4
    for (int j = 0; j < D; ++j) {
        const float xv = xT[j][lane];          // conflict-free ds_read_b32
        const float* wr = Wk + j * D;          // wave-uniform -> s_load x16
        #pragma unroll
        for (int cc = 0; cc < CCH; ++cc)
            acc[cc] = fmaf(xv, wr[cc], acc[cc]);  // v_fmac_f32 v, s, v
    }

    // epilogue: per-lane partials for this column chunk
    float tp = 0.0f, bp = 0.0f;
    #pragma unroll 4
    for (int cc = 0; cc < CCH; ++cc) {
        const float wm = Wm[k * D + c0 + cc];   // wave-uniform s_load
        tp = fmaf(fmaxf(acc[cc], 0.0f), wm, tp);
        bp = fmaf(xT[c0 + cc][lane], wm, bp);
    }
    redT[wave][lane] = tp;
    redB[wave][lane] = bp;
    __syncthreads();

    if (wave == 0) {
        const int idx = nbase + lane;
        if (idx < cnt) {
            const int id = list[idx];
            t32[(size_t)id * K + k]    = redT[0][lane] + redT[1][lane] +
                                         redT[2][lane] + redT[3][lane];
            base32[(size_t)id * K + k] = redB[0][lane] + redB[1][lane] +
                                         redB[2][lane] + redB[3][lane];
        }
    }
}

// ---------------------------------------------------------------------------
// Phase 2 (fp32): agg32[dst,k] += t32[src,k]. Lane = (edge, head): groups of
// 8 lanes cover one edge's 8 heads, so their atomics hit 8 consecutive
// floats (one 32 B sector -> hardware-merged; R5 WRITE_SIZE evidence).
// Gated by t!=0 (src masked) AND mb[dst] bit (agg dead if dst unmasked).
// ---------------------------------------------------------------------------
__global__ __launch_bounds__(256)
void scatter_kernel(const int* __restrict__ ei,
                    const unsigned char* __restrict__ mb,
                    const float* __restrict__ t32,
                    float* __restrict__ agg32)
{
    const long long tid = (long long)blockIdx.x * 256 + threadIdx.x;
    if (tid >= (long long)N_EDGES * K) return;
    const int k = (int)(tid & (K - 1));
    const long long e = tid >> 3;
    const int d = ei[(long long)N_EDGES + e];   // broadcast within 8-lane group
    const unsigned md = mb[d];
    if (!((md >> k) & 1)) return;
    const int s = ei[e];
    const float v = t32[(size_t)s * K + k];     // 32 B coalesced per group
    if (v != 0.0f) atomicAdd(&agg32[(size_t)d * K + k], v);
}

// ---------------------------------------------------------------------------
// Phase 3: tentative combine + flag near-zero scores for exact repair.
// head bool = (mask>0) && (score>0); output = first <=2 true heads (lax.top_k
// on all-equal norms tie-breaks by lowest index).
// ---------------------------------------------------------------------------
__global__ __launch_bounds__(256)
void combine_flag_kernel(const unsigned char* __restrict__ mb,
                         const float* __restrict__ base32,
                         const float* __restrict__ agg32,
                         float* __restrict__ out,
                         unsigned char* __restrict__ flag8)
{
    const int n = blockIdx.x * 256 + threadIdx.x;
    if (n >= N_NODES) return;
    const unsigned m8 = mb[n];
    float o[K];
    int cnt = 0, fl = 0;
    #pragma unroll
    for (int k = 0; k < K; ++k) {
        const float s = base32[(size_t)n * K + k] + agg32[(size_t)n * K + k];
        const bool masked = (m8 >> k) & 1;
        const bool hm = masked && (s > 0.0f);
        if (masked && fabsf(s) < TAU) fl |= (1 << k);
        o[k] = (hm && cnt < 2) ? 1.0f : 0.0f;
        cnt += hm ? 1 : 0;
    }
    float4* op = (float4*)(out + (size_t)n * K);
    op[0] = make_float4(o[0], o[1], o[2], o[3]);
    op[1] = make_float4(o[4], o[5], o[6], o[7]);
    flag8[n] = (unsigned char)fl;
}

// ---------------------------------------------------------------------------
// Repair A: edges into flagged (dst,k) with masked src -> worklist.
// ---------------------------------------------------------------------------
__global__ __launch_bounds__(256)
void edge_flag_kernel(const int* __restrict__ ei,
                      const unsigned char* __restrict__ mb,
                      const unsigned char* __restrict__ flag8,
                      int2* __restrict__ wl,
                      int* __restrict__ wlcnt)
{
    const int e = blockIdx.x * 256 + threadIdx.x;
    if (e >= N_EDGES) return;
    const int d = ei[(long long)N_EDGES + e];
    unsigned f = flag8[d];
    if (!f) return;
    const int s = ei[e];
    f &= mb[s];
    while (f) {
        const int k = __ffs(f) - 1;
        f &= f - 1;
        const int idx = atomicAdd(wlcnt, 1);
        if (idx < WL_CAP) wl[idx] = make_int2(s | (k << 20), d);
    }
}

// ---------------------------------------------------------------------------
// Repair B: one wave per worklist entry: exact fp64 t, atomic into score64.
// ---------------------------------------------------------------------------
__global__ __launch_bounds__(256)
void repair_t_kernel(const float* __restrict__ x,
                     const float* __restrict__ Ww,
                     const float* __restrict__ Wm,
                     const int2* __restrict__ wl,
                     const int* __restrict__ wlcnt,
                     double* __restrict__ score64)
{
    const int lane = threadIdx.x & 63;
    const int waveId = blockIdx.x * 4 + (threadIdx.x >> 6);
    const int nWaves = gridDim.x * 4;
    int cnt = *wlcnt;
    if (cnt > WL_CAP) cnt = WL_CAP;
    for (int w = waveId; w < cnt; w += nWaves) {
        const int2 ent = wl[w];
        const int s = __builtin_amdgcn_readfirstlane(ent.x & 0xFFFFF);
        const int k = __builtin_amdgcn_readfirstlane(ent.x >> 20);
        const int d = ent.y;
        const float* xr = x + (size_t)s * D;
        const float* Wk = Ww + (size_t)k * D * D;
        double c0 = 0.0, c1 = 0.0;
        for (int j = 0; j < D; ++j) {
            const double xd = (double)xr[j];
            c0 = fma(xd, (double)Wk[j * D + lane], c0);
            c1 = fma(xd, (double)Wk[j * D + lane + 64], c1);
        }
        double ts = fmax(c0, 0.0) * (double)Wm[k * D + lane]
                  + fmax(c1, 0.0) * (double)Wm[k * D + lane + 64];
        #pragma unroll
        for (int off = 32; off > 0; off >>= 1) ts += __shfl_xor(ts, off);
        if (lane == 0) atomicAdd(&score64[(size_t)d * K + k], ts);
    }
}

// ---------------------------------------------------------------------------
// Repair C: rewrite output rows of flagged nodes using exact scores.
// ---------------------------------------------------------------------------
__global__ __launch_bounds__(256)
void repair_combine_kernel(const float* __restrict__ x,
                           const unsigned char* __restrict__ mb,
                           const float* __restrict__ Wm,
                           const float* __restrict__ base32,
                           const float* __restrict__ agg32,
                           const double* __restrict__ score64,
                           const unsigned char* __restrict__ flag8,
                           float* __restrict__ out)
{
    const int n = blockIdx.x * 256 + threadIdx.x;
    if (n >= N_NODES) return;
    const unsigned f = flag8[n];
    if (!f) return;
    const unsigned m8 = mb[n];
    float o[K];
    int cnt = 0;
    #pragma unroll
    for (int k = 0; k < K; ++k) {
        bool hm;
        if ((f >> k) & 1) {
            double b = 0.0;
            for (int j = 0; j < D; ++j)
                b = fma((double)x[(size_t)n * D + j], (double)Wm[k * D + j], b);
            hm = (b + score64[(size_t)n * K + k]) > 0.0;
        } else {
            hm = ((m8 >> k) & 1) &&
                 ((base32[(size_t)n * K + k] + agg32[(size_t)n * K + k]) > 0.0f);
        }
        o[k] = (hm && cnt < 2) ? 1.0f : 0.0f;
        cnt += hm ? 1 : 0;
    }
    float4* op = (float4*)(out + (size_t)n * K);
    op[0] = make_float4(o[0], o[1], o[2], o[3]);
    op[1] = make_float4(o[4], o[5], o[6], o[7]);
}

extern "C" void kernel_launch(void* const* d_in, const int* in_sizes, int n_in,
                              void* d_out, int out_size, void* d_ws, size_t ws_size,
                              hipStream_t stream)
{
    const float* x    = (const float*)d_in[0];
    const int*   ei   = (const int*)d_in[1];   // edge_index [2, E] int32
    const float* mask = (const float*)d_in[2]; // [N, K]
    const float* Ww   = (const float*)d_in[3]; // [K, D, D]
    const float* Wm   = (const float*)d_in[4]; // [K, D, 1]
    float* out = (float*)d_out;                // [N, K] float32

    // workspace layout:
    //   [0, 3.2M)            t32      f32[N*K]
    //   [3.2M, 6.4M)         agg32    f32[N*K]
    //   [6.4M, 12.8M)        s64      f64[N*K]  (early: lists int[K][N], 3.2M)
    //   [12.8M, +100000)     flag8    u8[N]
    //   [12,900,000, +32)    cnts     int[8]
    //   [12,900,032, +4+pad) wlcnt    int
    //   [12,900,040, +2M)    wl       int2[WL_CAP]
    //   [14,997,192, +3.2M)  base32   f32[N*K]
    //   [18,197,192, +100000) mb      u8[N]      (end ~18.3 MB)
    char* w = (char*)d_ws;
    float*         t32    = (float*)w;
    float*         agg32  = (float*)(w + 3200000);
    double*        s64    = (double*)(w + 6400000);
    int*           lists  = (int*)(w + 6400000);       // overlays s64 (dead then)
    unsigned char* flag8  = (unsigned char*)(w + 12800000);
    int*           cnts   = (int*)(w + 12900000);
    int*           wlcnt  = (int*)(w + 12900032);
    int2*          wl     = (int2*)(w + 12900040);
    float*         b32    = (float*)(w + 12900040 + (size_t)WL_CAP * 8);
    unsigned char* mb     = (unsigned char*)(w + 12900040 + (size_t)WL_CAP * 8 + 3200000);

    // zero t32|agg32 and flag8|cnts|wlcnt (s64 zeroed later, after gemm)
    hipMemsetAsync(w, 0, 6400000, stream);
    hipMemsetAsync(w + 12800000, 0, 100040, stream);

    compact_kernel<<<(N_NODES + 255) / 256, 256, 0, stream>>>(mask, lists, cnts, mb);

    // grid: chunks padded to x8 so bid = c0*64 + h*8 + clo covers all (c,h)
    const int nchunks = (N_NODES + CHUNK - 1) / CHUNK;          // 1563
    const int nc8 = (nchunks + 7) & ~7;                          // 1568
    head_gemm_kernel<<<nc8 * K, 256, 0, stream>>>(x, Ww, Wm, lists, cnts, t32, b32);

    const long long nek = (long long)N_EDGES * K;
    scatter_kernel<<<(int)((nek + 255) / 256), 256, 0, stream>>>(ei, mb, t32, agg32);

    combine_flag_kernel<<<(N_NODES + 255) / 256, 256, 0, stream>>>(
        mb, b32, agg32, out, flag8);

    // lists dead now; zero s64 for exact re-accumulation
    hipMemsetAsync(s64, 0, 6400000, stream);

    edge_flag_kernel<<<(N_EDGES + 255) / 256, 256, 0, stream>>>(
        ei, mb, flag8, wl, wlcnt);

    repair_t_kernel<<<512, 256, 0, stream>>>(x, Ww, Wm, wl, wlcnt, s64);

    repair_combine_kernel<<<(N_NODES + 255) / 256, 256, 0, stream>>>(
        x, mb, Wm, b32, agg32, s64, flag8, out);
}

// Round 7
// 551.420 us; speedup vs baseline: 1.5759x; 1.2539x over previous
//
#include <hip/hip_runtime.h>

#define N_NODES 100000
#define N_EDGES 3200000
#define D 128
#define K 8

// |score32| below this => exact fp64 repair. fp32 score error sigma ~1e-5,
// so 2e-3 is ~200 sigma: no sign flip can survive unflagged.
#define TAU 2e-3f
#define WL_CAP 262144  // repair worklist capacity

#define CHUNK 64   // nodes per head_gemm block
#define CCH   16   // output columns per wave (8 waves x 16 = 128)
#define GWAVES 8   // waves per head_gemm block (512 threads)

// ---------------------------------------------------------------------------
// Phase 0: per-head compaction of masked node ids + per-node mask bitmap.
// Block-aggregated counter atomics: 4 wave counts -> LDS -> ONE atomicAdd per
// (block, k) instead of one per (wave, k) — R6 had 6.3k atomics per hot
// counter address; this cuts per-address contention 4x.
// ---------------------------------------------------------------------------
__global__ __launch_bounds__(256)
void compact_kernel(const float* __restrict__ mask,
                    int* __restrict__ lists,
                    int* __restrict__ cnts,
                    unsigned char* __restrict__ mb)
{
    __shared__ int wcnt[4][K];
    __shared__ int wbase[4][K];

    const int n = blockIdx.x * 256 + threadIdx.x;
    const int lane = threadIdx.x & 63;
    const int wave = threadIdx.x >> 6;
    const bool valid = (n < N_NODES);

    unsigned long long ball[K];
    int bits8 = 0;
    #pragma unroll
    for (int k = 0; k < K; ++k) {
        const bool m = valid && (mask[(size_t)n * K + k] > 0.0f);
        bits8 |= m ? (1 << k) : 0;
        ball[k] = __ballot(m);
        if (lane == 0) wcnt[wave][k] = __popcll(ball[k]);
    }
    __syncthreads();

    if (threadIdx.x < K) {
        const int k = threadIdx.x;
        const int t0 = wcnt[0][k], t1 = wcnt[1][k], t2 = wcnt[2][k], t3 = wcnt[3][k];
        const int base = (t0 + t1 + t2 + t3)
                       ? atomicAdd(&cnts[k], t0 + t1 + t2 + t3) : 0;
        wbase[0][k] = base;
        wbase[1][k] = base + t0;
        wbase[2][k] = base + t0 + t1;
        wbase[3][k] = base + t0 + t1 + t2;
    }
    __syncthreads();

    #pragma unroll
    for (int k = 0; k < K; ++k) {
        if ((ball[k] >> lane) & 1ull) {
            const int pos = __popcll(ball[k] & ((1ull << lane) - 1ull));
            lists[(size_t)k * N_NODES + wbase[wave][k] + pos] = n;
        }
    }
    if (valid) mb[n] = (unsigned char)bits8;
}

// ---------------------------------------------------------------------------
// Phase 1 (fp32): for each compacted (node,head):
//   t32[n,k]    = relu(x[n] @ Ww_k) . Wm_k
//   base32[n,k] = x[n] . Wm_k
// Block = 64 nodes x 1 head, 512 threads (8 waves x 16 cols). xT transposed
// in LDS (37 KB -> 4 blocks/CU = 8 waves/SIMD: hides the ~200-cyc SMEM
// latency of the per-j W row that capped R6 at VALUBusy 50%). Lane = node;
// per j: one conflict-free ds_read_b32 + 16 s-operand fmacs (W row
// wave-uniform -> batched s_load; 16 floats/row halves SGPR pressure vs R6).
// Grid swizzle: bid = c0*64 + h*8 + clo -> the 8 heads of one node-chunk
// share bid%8 (same XCD), adjacent in dispatch -> x reused from that L2.
// ---------------------------------------------------------------------------
__global__ __launch_bounds__(512, 8)
void head_gemm_kernel(const float* __restrict__ x,
                      const float* __restrict__ Ww,
                      const float* __restrict__ Wm,
                      const int* __restrict__ lists,
                      const int* __restrict__ cnts,
                      float* __restrict__ t32,
                      float* __restrict__ base32)
{
    __shared__ float xT[D][CHUNK + 1];   // 33.3 KB
    __shared__ float redT[GWAVES][CHUNK];
    __shared__ float redB[GWAVES][CHUNK];

    const int bid = blockIdx.x;
    const int k = (bid >> 3) & 7;
    const int c = ((bid >> 6) << 3) | (bid & 7);

    const int cnt = cnts[k];
    const int nbase = c * CHUNK;
    if (nbase >= cnt) return;            // block-uniform exit (before barriers)

    const int lane = threadIdx.x & 63;
    const int wave = __builtin_amdgcn_readfirstlane((int)(threadIdx.x >> 6));
    const int* list = lists + (size_t)k * N_NODES;

    // stage 8 rows per wave, transposed; clamp tail (duplicate rows harmless)
    #pragma unroll
    for (int i = 0; i < 8; ++i) {
        const int r = wave * 8 + i;
        int idx = nbase + r;
        if (idx >= cnt) idx = cnt - 1;
        const int id = __builtin_amdgcn_readfirstlane(list[idx]);
        xT[lane][r]      = x[(size_t)id * D + lane];        // 256 B coalesced
        xT[lane + 64][r] = x[(size_t)id * D + lane + 64];
    }
    __syncthreads();

    const int c0 = wave * CCH;
    const float* Wk = Ww + (size_t)k * D * D + c0;

    float acc[CCH];
    #pragma unroll
    for (int cc = 0; cc < CCH; ++cc) acc[cc] = 0.0f;

    #pragma unroll 4
    for (int j = 0; j < D; ++j) {
        const float xv = xT[j][lane];          // conflict-free ds_read_b32
        const float* wr = Wk + j * D;          // wave-uniform -> s_load x16
        #pragma unroll
        for (int cc = 0; cc < CCH; ++cc)
            acc[cc] = fmaf(xv, wr[cc], acc[cc]);  // v_fmac_f32 v, s, v
    }

    // epilogue: per-lane partials for this column chunk
    float tp = 0.0f, bp = 0.0f;
    #pragma unroll 4
    for (int cc = 0; cc < CCH; ++cc) {
        const float wm = Wm[k * D + c0 + cc];   // wave-uniform s_load
        tp = fmaf(fmaxf(acc[cc], 0.0f), wm, tp);
        bp = fmaf(xT[c0 + cc][lane], wm, bp);
    }
    redT[wave][lane] = tp;
    redB[wave][lane] = bp;
    __syncthreads();

    if (wave == 0) {
        const int idx = nbase + lane;
        if (idx < cnt) {
            const int id = list[idx];
            float ts = 0.0f, bs = 0.0f;
            #pragma unroll
            for (int wv = 0; wv < GWAVES; ++wv) {
                ts += redT[wv][lane];
                bs += redB[wv][lane];
            }
            t32[(size_t)id * K + k]    = ts;
            base32[(size_t)id * K + k] = bs;
        }
    }
}

// ---------------------------------------------------------------------------
// Phase 2 (fp32): agg32[dst,k] += t32[src,k]. Lane = (edge, head): groups of
// 8 lanes cover one edge's 8 heads, so their atomics hit 8 consecutive
// floats (one 32 B sector -> hardware-merged; R5 WRITE_SIZE evidence).
// Gated by t!=0 (src masked) AND mb[dst] bit (agg dead if dst unmasked).
// ---------------------------------------------------------------------------
__global__ __launch_bounds__(256)
void scatter_kernel(const int* __restrict__ ei,
                    const unsigned char* __restrict__ mb,
                    const float* __restrict__ t32,
                    float* __restrict__ agg32)
{
    const long long tid = (long long)blockIdx.x * 256 + threadIdx.x;
    if (tid >= (long long)N_EDGES * K) return;
    const int k = (int)(tid & (K - 1));
    const long long e = tid >> 3;
    const int d = ei[(long long)N_EDGES + e];   // broadcast within 8-lane group
    const unsigned md = mb[d];
    if (!((md >> k) & 1)) return;
    const int s = ei[e];
    const float v = t32[(size_t)s * K + k];     // 32 B coalesced per group
    if (v != 0.0f) atomicAdd(&agg32[(size_t)d * K + k], v);
}

// ---------------------------------------------------------------------------
// Phase 3: tentative combine + flag near-zero scores for exact repair.
// head bool = (mask>0) && (score>0); output = first <=2 true heads (lax.top_k
// on all-equal norms tie-breaks by lowest index).
// ---------------------------------------------------------------------------
__global__ __launch_bounds__(256)
void combine_flag_kernel(const unsigned char* __restrict__ mb,
                         const float* __restrict__ base32,
                         const float* __restrict__ agg32,
                         float* __restrict__ out,
                         unsigned char* __restrict__ flag8)
{
    const int n = blockIdx.x * 256 + threadIdx.x;
    if (n >= N_NODES) return;
    const unsigned m8 = mb[n];
    float o[K];
    int cnt = 0, fl = 0;
    #pragma unroll
    for (int k = 0; k < K; ++k) {
        const float s = base32[(size_t)n * K + k] + agg32[(size_t)n * K + k];
        const bool masked = (m8 >> k) & 1;
        const bool hm = masked && (s > 0.0f);
        if (masked && fabsf(s) < TAU) fl |= (1 << k);
        o[k] = (hm && cnt < 2) ? 1.0f : 0.0f;
        cnt += hm ? 1 : 0;
    }
    float4* op = (float4*)(out + (size_t)n * K);
    op[0] = make_float4(o[0], o[1], o[2], o[3]);
    op[1] = make_float4(o[4], o[5], o[6], o[7]);
    flag8[n] = (unsigned char)fl;
}

// ---------------------------------------------------------------------------
// Repair A: edges into flagged (dst,k) with masked src -> worklist.
// ---------------------------------------------------------------------------
__global__ __launch_bounds__(256)
void edge_flag_kernel(const int* __restrict__ ei,
                      const unsigned char* __restrict__ mb,
                      const unsigned char* __restrict__ flag8,
                      int2* __restrict__ wl,
                      int* __restrict__ wlcnt)
{
    const int e = blockIdx.x * 256 + threadIdx.x;
    if (e >= N_EDGES) return;
    const int d = ei[(long long)N_EDGES + e];
    unsigned f = flag8[d];
    if (!f) return;
    const int s = ei[e];
    f &= mb[s];
    while (f) {
        const int k = __ffs(f) - 1;
        f &= f - 1;
        const int idx = atomicAdd(wlcnt, 1);
        if (idx < WL_CAP) wl[idx] = make_int2(s | (k << 20), d);
    }
}

// ---------------------------------------------------------------------------
// Repair B: one wave per worklist entry: exact fp64 t, atomic into score64.
// ---------------------------------------------------------------------------
__global__ __launch_bounds__(256)
void repair_t_kernel(const float* __restrict__ x,
                     const float* __restrict__ Ww,
                     const float* __restrict__ Wm,
                     const int2* __restrict__ wl,
                     const int* __restrict__ wlcnt,
                     double* __restrict__ score64)
{
    const int lane = threadIdx.x & 63;
    const int waveId = blockIdx.x * 4 + (threadIdx.x >> 6);
    const int nWaves = gridDim.x * 4;
    int cnt = *wlcnt;
    if (cnt > WL_CAP) cnt = WL_CAP;
    for (int w = waveId; w < cnt; w += nWaves) {
        const int2 ent = wl[w];
        const int s = __builtin_amdgcn_readfirstlane(ent.x & 0xFFFFF);
        const int k = __builtin_amdgcn_readfirstlane(ent.x >> 20);
        const int d = ent.y;
        const float* xr = x + (size_t)s * D;
        const float* Wk = Ww + (size_t)k * D * D;
        double c0 = 0.0, c1 = 0.0;
        for (int j = 0; j < D; ++j) {
            const double xd = (double)xr[j];
            c0 = fma(xd, (double)Wk[j * D + lane], c0);
            c1 = fma(xd, (double)Wk[j * D + lane + 64], c1);
        }
        double ts = fmax(c0, 0.0) * (double)Wm[k * D + lane]
                  + fmax(c1, 0.0) * (double)Wm[k * D + lane + 64];
        #pragma unroll
        for (int off = 32; off > 0; off >>= 1) ts += __shfl_xor(ts, off);
        if (lane == 0) atomicAdd(&score64[(size_t)d * K + k], ts);
    }
}

// ---------------------------------------------------------------------------
// Repair C: rewrite output rows of flagged nodes using exact scores.
// ---------------------------------------------------------------------------
__global__ __launch_bounds__(256)
void repair_combine_kernel(const float* __restrict__ x,
                           const unsigned char* __restrict__ mb,
                           const float* __restrict__ Wm,
                           const float* __restrict__ base32,
                           const float* __restrict__ agg32,
                           const double* __restrict__ score64,
                           const unsigned char* __restrict__ flag8,
                           float* __restrict__ out)
{
    const int n = blockIdx.x * 256 + threadIdx.x;
    if (n >= N_NODES) return;
    const unsigned f = flag8[n];
    if (!f) return;
    const unsigned m8 = mb[n];
    float o[K];
    int cnt = 0;
    #pragma unroll
    for (int k = 0; k < K; ++k) {
        bool hm;
        if ((f >> k) & 1) {
            double b = 0.0;
            for (int j = 0; j < D; ++j)
                b = fma((double)x[(size_t)n * D + j], (double)Wm[k * D + j], b);
            hm = (b + score64[(size_t)n * K + k]) > 0.0;
        } else {
            hm = ((m8 >> k) & 1) &&
                 ((base32[(size_t)n * K + k] + agg32[(size_t)n * K + k]) > 0.0f);
        }
        o[k] = (hm && cnt < 2) ? 1.0f : 0.0f;
        cnt += hm ? 1 : 0;
    }
    float4* op = (float4*)(out + (size_t)n * K);
    op[0] = make_float4(o[0], o[1], o[2], o[3]);
    op[1] = make_float4(o[4], o[5], o[6], o[7]);
}

extern "C" void kernel_launch(void* const* d_in, const int* in_sizes, int n_in,
                              void* d_out, int out_size, void* d_ws, size_t ws_size,
                              hipStream_t stream)
{
    const float* x    = (const float*)d_in[0];
    const int*   ei   = (const int*)d_in[1];   // edge_index [2, E] int32
    const float* mask = (const float*)d_in[2]; // [N, K]
    const float* Ww   = (const float*)d_in[3]; // [K, D, D]
    const float* Wm   = (const float*)d_in[4]; // [K, D, 1]
    float* out = (float*)d_out;                // [N, K] float32

    // workspace layout:
    //   [0, 3.2M)            t32      f32[N*K]
    //   [3.2M, 6.4M)         agg32    f32[N*K]
    //   [6.4M, 12.8M)        s64      f64[N*K]  (early: lists int[K][N], 3.2M)
    //   [12.8M, +100000)     flag8    u8[N]
    //   [12,900,000, +32)    cnts     int[8]
    //   [12,900,032, +4+pad) wlcnt    int
    //   [12,900,040, +2M)    wl       int2[WL_CAP]
    //   [14,997,192, +3.2M)  base32   f32[N*K]
    //   [18,197,192, +100000) mb      u8[N]      (end ~18.3 MB)
    char* w = (char*)d_ws;
    float*         t32    = (float*)w;
    float*         agg32  = (float*)(w + 3200000);
    double*        s64    = (double*)(w + 6400000);
    int*           lists  = (int*)(w + 6400000);       // overlays s64 (dead then)
    unsigned char* flag8  = (unsigned char*)(w + 12800000);
    int*           cnts   = (int*)(w + 12900000);
    int*           wlcnt  = (int*)(w + 12900032);
    int2*          wl     = (int2*)(w + 12900040);
    float*         b32    = (float*)(w + 12900040 + (size_t)WL_CAP * 8);
    unsigned char* mb     = (unsigned char*)(w + 12900040 + (size_t)WL_CAP * 8 + 3200000);

    // zero t32|agg32 and flag8|cnts|wlcnt (s64 zeroed later, after gemm)
    hipMemsetAsync(w, 0, 6400000, stream);
    hipMemsetAsync(w + 12800000, 0, 100040, stream);

    compact_kernel<<<(N_NODES + 255) / 256, 256, 0, stream>>>(mask, lists, cnts, mb);

    // grid: chunks padded to x8 so bid = c0*64 + h*8 + clo covers all (c,h)
    const int nchunks = (N_NODES + CHUNK - 1) / CHUNK;          // 1563
    const int nc8 = (nchunks + 7) & ~7;                          // 1568
    head_gemm_kernel<<<nc8 * K, 512, 0, stream>>>(x, Ww, Wm, lists, cnts, t32, b32);

    const long long nek = (long long)N_EDGES * K;
    scatter_kernel<<<(int)((nek + 255) / 256), 256, 0, stream>>>(ei, mb, t32, agg32);

    combine_flag_kernel<<<(N_NODES + 255) / 256, 256, 0, stream>>>(
        mb, b32, agg32, out, flag8);

    // lists dead now; zero s64 for exact re-accumulation
    hipMemsetAsync(s64, 0, 6400000, stream);

    edge_flag_kernel<<<(N_EDGES + 255) / 256, 256, 0, stream>>>(
        ei, mb, flag8, wl, wlcnt);

    repair_t_kernel<<<512, 256, 0, stream>>>(x, Ww, Wm, wl, wlcnt, s64);

    repair_combine_kernel<<<(N_NODES + 255) / 256, 256, 0, stream>>>(
        x, mb, Wm, b32, agg32, s64, flag8, out);
}

// Round 8
// 515.620 us; speedup vs baseline: 1.6854x; 1.0694x over previous
//
#include <hip/hip_runtime.h>

#define N_NODES 100000
#define N_EDGES 3200000
#define D 128
#define K 8

// |score32| below this => exact fp64 repair. fp32 score error sigma ~1e-5,
// so 2e-3 is ~200 sigma: no sign flip can survive unflagged.
#define TAU 2e-3f
#define WL_CAP 262144  // repair worklist capacity

#define CHUNK 128  // nodes per head_gemm block (2 subgroups of 64)
#define CCH   16   // output columns per wave (8 waves x 16 = 128)
#define GWAVES 8   // waves per head_gemm block (512 threads)
#define JHALF 64   // j-rows staged per pass (2 passes cover D=128)

// ---------------------------------------------------------------------------
// Phase 0: per-head compaction of masked node ids + per-node mask bitmap.
// Block-aggregated counter atomics (R7: cut per-address contention 4x,
// worth ~140 us).
// ---------------------------------------------------------------------------
__global__ __launch_bounds__(256)
void compact_kernel(const float* __restrict__ mask,
                    int* __restrict__ lists,
                    int* __restrict__ cnts,
                    unsigned char* __restrict__ mb)
{
    __shared__ int wcnt[4][K];
    __shared__ int wbase[4][K];

    const int n = blockIdx.x * 256 + threadIdx.x;
    const int lane = threadIdx.x & 63;
    const int wave = threadIdx.x >> 6;
    const bool valid = (n < N_NODES);

    unsigned long long ball[K];
    int bits8 = 0;
    #pragma unroll
    for (int k = 0; k < K; ++k) {
        const bool m = valid && (mask[(size_t)n * K + k] > 0.0f);
        bits8 |= m ? (1 << k) : 0;
        ball[k] = __ballot(m);
        if (lane == 0) wcnt[wave][k] = __popcll(ball[k]);
    }
    __syncthreads();

    if (threadIdx.x < K) {
        const int k = threadIdx.x;
        const int t0 = wcnt[0][k], t1 = wcnt[1][k], t2 = wcnt[2][k], t3 = wcnt[3][k];
        const int base = (t0 + t1 + t2 + t3)
                       ? atomicAdd(&cnts[k], t0 + t1 + t2 + t3) : 0;
        wbase[0][k] = base;
        wbase[1][k] = base + t0;
        wbase[2][k] = base + t0 + t1;
        wbase[3][k] = base + t0 + t1 + t2;
    }
    __syncthreads();

    #pragma unroll
    for (int k = 0; k < K; ++k) {
        if ((ball[k] >> lane) & 1ull) {
            const int pos = __popcll(ball[k] & ((1ull << lane) - 1ull));
            lists[(size_t)k * N_NODES + wbase[wave][k] + pos] = n;
        }
    }
    if (valid) mb[n] = (unsigned char)bits8;
}

// ---------------------------------------------------------------------------
// Phase 1 (fp32): for each compacted (node,head):
//   t32[n,k]    = relu(x[n] @ Ww_k) . Wm_k
//   base32[n,k] = x[n] . Wm_k
// Block = 128 nodes x 1 head, 512 threads (8 waves x 16 cols). R7 showed the
// cap is the scalar-fetch path (W row s_loads miss the 16 KB K$): R6/R7 both
// ran 4 B SMEM per fmac and both hit ~52% VALU at ~205 us regardless of
// occupancy. Here each 64 B W-row s_load feeds 32 fmacs (two 64-node
// subgroups) -> 2 B/fmac, and per-block W traffic amortizes over 2x nodes
// (total scalar traffic halves). K-dim split into 2 passes of 64 j with xT
// re-staged (33 KB + 8 KB red -> 41 KB -> 3 blocks/CU).
// Grid swizzle: the 8 heads of one node-chunk share bid%8 (same XCD).
// ---------------------------------------------------------------------------
__global__ __launch_bounds__(512, 6)
void head_gemm_kernel(const float* __restrict__ x,
                      const float* __restrict__ Ww,
                      const float* __restrict__ Wm,
                      const int* __restrict__ lists,
                      const int* __restrict__ cnts,
                      float* __restrict__ t32,
                      float* __restrict__ base32)
{
    __shared__ float xT[JHALF][CHUNK + 2];   // 64 x 130 floats = 33.3 KB
    __shared__ float redT[GWAVES][CHUNK];    // 4 KB
    __shared__ float redB[GWAVES][CHUNK];    // 4 KB

    const int bid = blockIdx.x;
    const int k = (bid >> 3) & 7;
    const int c = ((bid >> 6) << 3) | (bid & 7);

    const int cnt = cnts[k];
    const int nbase = c * CHUNK;
    if (nbase >= cnt) return;            // block-uniform exit (before barriers)

    const int lane = threadIdx.x & 63;
    const int wave = __builtin_amdgcn_readfirstlane((int)(threadIdx.x >> 6));
    const int* list = lists + (size_t)k * N_NODES;

    const int c0 = wave * CCH;
    const float* Wk = Ww + (size_t)k * D * D + c0;

    float acc0[CCH], acc1[CCH];
    #pragma unroll
    for (int cc = 0; cc < CCH; ++cc) { acc0[cc] = 0.0f; acc1[cc] = 0.0f; }
    float bp0 = 0.0f, bp1 = 0.0f;

    #pragma unroll
    for (int p = 0; p < 2; ++p) {
        // stage 16 node-rows per wave for j in [p*64, p*64+64)
        #pragma unroll
        for (int i = 0; i < 16; ++i) {
            const int r = wave * 16 + i;
            int idx = nbase + r;
            if (idx >= cnt) idx = cnt - 1;    // dup tail rows (writes guarded)
            const int id = __builtin_amdgcn_readfirstlane(list[idx]);
            xT[lane][r] = x[(size_t)id * D + p * JHALF + lane]; // 256 B coalesced
        }
        __syncthreads();

        #pragma unroll 4
        for (int jl = 0; jl < JHALF; ++jl) {
            const float xv0 = xT[jl][lane];        // conflict-free ds_read
            const float xv1 = xT[jl][lane + 64];
            const float* wr = Wk + (p * JHALF + jl) * D;  // wave-uniform s_load
            #pragma unroll
            for (int cc = 0; cc < CCH; ++cc) {
                const float wv = wr[cc];
                acc0[cc] = fmaf(xv0, wv, acc0[cc]);
                acc1[cc] = fmaf(xv1, wv, acc1[cc]);
            }
        }

        // base partial: this wave's j-columns [c0, c0+16) live in pass c0/64
        if ((c0 >> 6) == p) {
            const int jb = c0 & (JHALF - 1);
            #pragma unroll
            for (int cc = 0; cc < CCH; ++cc) {
                const float wm = Wm[k * D + c0 + cc];
                bp0 = fmaf(xT[jb + cc][lane], wm, bp0);
                bp1 = fmaf(xT[jb + cc][lane + 64], wm, bp1);
            }
        }
        __syncthreads();   // xT consumed; safe to restage next pass
    }

    // t partial (relu then dot with Wm over this wave's columns)
    float tp0 = 0.0f, tp1 = 0.0f;
    #pragma unroll
    for (int cc = 0; cc < CCH; ++cc) {
        const float wm = Wm[k * D + c0 + cc];
        tp0 = fmaf(fmaxf(acc0[cc], 0.0f), wm, tp0);
        tp1 = fmaf(fmaxf(acc1[cc], 0.0f), wm, tp1);
    }
    redT[wave][lane]      = tp0;
    redT[wave][lane + 64] = tp1;
    redB[wave][lane]      = bp0;
    redB[wave][lane + 64] = bp1;
    __syncthreads();

    if (wave < 2) {
        const int r = wave * 64 + lane;          // node-slot 0..127
        const int idx = nbase + r;
        if (idx < cnt) {
            const int id = list[idx];
            float ts = 0.0f, bs = 0.0f;
            #pragma unroll
            for (int wv = 0; wv < GWAVES; ++wv) {
                ts += redT[wv][r];
                bs += redB[wv][r];
            }
            t32[(size_t)id * K + k]    = ts;
            base32[(size_t)id * K + k] = bs;
        }
    }
}

// ---------------------------------------------------------------------------
// Phase 2 (fp32): agg32[dst,k] += t32[src,k]. Lane = (edge, head): groups of
// 8 lanes cover one edge's 8 heads, so their atomics hit 8 consecutive
// floats (one 32 B sector -> hardware-merged; R5 WRITE_SIZE evidence).
// Gated by t!=0 (src masked) AND mb[dst] bit (agg dead if dst unmasked).
// ---------------------------------------------------------------------------
__global__ __launch_bounds__(256)
void scatter_kernel(const int* __restrict__ ei,
                    const unsigned char* __restrict__ mb,
                    const float* __restrict__ t32,
                    float* __restrict__ agg32)
{
    const long long tid = (long long)blockIdx.x * 256 + threadIdx.x;
    if (tid >= (long long)N_EDGES * K) return;
    const int k = (int)(tid & (K - 1));
    const long long e = tid >> 3;
    const int d = ei[(long long)N_EDGES + e];   // broadcast within 8-lane group
    const unsigned md = mb[d];
    if (!((md >> k) & 1)) return;
    const int s = ei[e];
    const float v = t32[(size_t)s * K + k];     // 32 B coalesced per group
    if (v != 0.0f) atomicAdd(&agg32[(size_t)d * K + k], v);
}

// ---------------------------------------------------------------------------
// Phase 3: tentative combine + flag near-zero scores for exact repair.
// head bool = (mask>0) && (score>0); output = first <=2 true heads (lax.top_k
// on all-equal norms tie-breaks by lowest index).
// ---------------------------------------------------------------------------
__global__ __launch_bounds__(256)
void combine_flag_kernel(const unsigned char* __restrict__ mb,
                         const float* __restrict__ base32,
                         const float* __restrict__ agg32,
                         float* __restrict__ out,
                         unsigned char* __restrict__ flag8)
{
    const int n = blockIdx.x * 256 + threadIdx.x;
    if (n >= N_NODES) return;
    const unsigned m8 = mb[n];
    float o[K];
    int cnt = 0, fl = 0;
    #pragma unroll
    for (int k = 0; k < K; ++k) {
        const float s = base32[(size_t)n * K + k] + agg32[(size_t)n * K + k];
        const bool masked = (m8 >> k) & 1;
        const bool hm = masked && (s > 0.0f);
        if (masked && fabsf(s) < TAU) fl |= (1 << k);
        o[k] = (hm && cnt < 2) ? 1.0f : 0.0f;
        cnt += hm ? 1 : 0;
    }
    float4* op = (float4*)(out + (size_t)n * K);
    op[0] = make_float4(o[0], o[1], o[2], o[3]);
    op[1] = make_float4(o[4], o[5], o[6], o[7]);
    flag8[n] = (unsigned char)fl;
}

// ---------------------------------------------------------------------------
// Repair A: edges into flagged (dst,k) with masked src -> worklist.
// ---------------------------------------------------------------------------
__global__ __launch_bounds__(256)
void edge_flag_kernel(const int* __restrict__ ei,
                      const unsigned char* __restrict__ mb,
                      const unsigned char* __restrict__ flag8,
                      int2* __restrict__ wl,
                      int* __restrict__ wlcnt)
{
    const int e = blockIdx.x * 256 + threadIdx.x;
    if (e >= N_EDGES) return;
    const int d = ei[(long long)N_EDGES + e];
    unsigned f = flag8[d];
    if (!f) return;
    const int s = ei[e];
    f &= mb[s];
    while (f) {
        const int k = __ffs(f) - 1;
        f &= f - 1;
        const int idx = atomicAdd(wlcnt, 1);
        if (idx < WL_CAP) wl[idx] = make_int2(s | (k << 20), d);
    }
}

// ---------------------------------------------------------------------------
// Repair B: one wave per worklist entry: exact fp64 t, atomic into score64.
// ---------------------------------------------------------------------------
__global__ __launch_bounds__(256)
void repair_t_kernel(const float* __restrict__ x,
                     const float* __restrict__ Ww,
                     const float* __restrict__ Wm,
                     const int2* __restrict__ wl,
                     const int* __restrict__ wlcnt,
                     double* __restrict__ score64)
{
    const int lane = threadIdx.x & 63;
    const int waveId = blockIdx.x * 4 + (threadIdx.x >> 6);
    const int nWaves = gridDim.x * 4;
    int cnt = *wlcnt;
    if (cnt > WL_CAP) cnt = WL_CAP;
    for (int w = waveId; w < cnt; w += nWaves) {
        const int2 ent = wl[w];
        const int s = __builtin_amdgcn_readfirstlane(ent.x & 0xFFFFF);
        const int k = __builtin_amdgcn_readfirstlane(ent.x >> 20);
        const int d = ent.y;
        const float* xr = x + (size_t)s * D;
        const float* Wk = Ww + (size_t)k * D * D;
        double c0 = 0.0, c1 = 0.0;
        for (int j = 0; j < D; ++j) {
            const double xd = (double)xr[j];
            c0 = fma(xd, (double)Wk[j * D + lane], c0);
            c1 = fma(xd, (double)Wk[j * D + lane + 64], c1);
        }
        double ts = fmax(c0, 0.0) * (double)Wm[k * D + lane]
                  + fmax(c1, 0.0) * (double)Wm[k * D + lane + 64];
        #pragma unroll
        for (int off = 32; off > 0; off >>= 1) ts += __shfl_xor(ts, off);
        if (lane == 0) atomicAdd(&score64[(size_t)d * K + k], ts);
    }
}

// ---------------------------------------------------------------------------
// Repair C: rewrite output rows of flagged nodes using exact scores.
// ---------------------------------------------------------------------------
__global__ __launch_bounds__(256)
void repair_combine_kernel(const float* __restrict__ x,
                           const unsigned char* __restrict__ mb,
                           const float* __restrict__ Wm,
                           const float* __restrict__ base32,
                           const float* __restrict__ agg32,
                           const double* __restrict__ score64,
                           const unsigned char* __restrict__ flag8,
                           float* __restrict__ out)
{
    const int n = blockIdx.x * 256 + threadIdx.x;
    if (n >= N_NODES) return;
    const unsigned f = flag8[n];
    if (!f) return;
    const unsigned m8 = mb[n];
    float o[K];
    int cnt = 0;
    #pragma unroll
    for (int k = 0; k < K; ++k) {
        bool hm;
        if ((f >> k) & 1) {
            double b = 0.0;
            for (int j = 0; j < D; ++j)
                b = fma((double)x[(size_t)n * D + j], (double)Wm[k * D + j], b);
            hm = (b + score64[(size_t)n * K + k]) > 0.0;
        } else {
            hm = ((m8 >> k) & 1) &&
                 ((base32[(size_t)n * K + k] + agg32[(size_t)n * K + k]) > 0.0f);
        }
        o[k] = (hm && cnt < 2) ? 1.0f : 0.0f;
        cnt += hm ? 1 : 0;
    }
    float4* op = (float4*)(out + (size_t)n * K);
    op[0] = make_float4(o[0], o[1], o[2], o[3]);
    op[1] = make_float4(o[4], o[5], o[6], o[7]);
}

extern "C" void kernel_launch(void* const* d_in, const int* in_sizes, int n_in,
                              void* d_out, int out_size, void* d_ws, size_t ws_size,
                              hipStream_t stream)
{
    const float* x    = (const float*)d_in[0];
    const int*   ei   = (const int*)d_in[1];   // edge_index [2, E] int32
    const float* mask = (const float*)d_in[2]; // [N, K]
    const float* Ww   = (const float*)d_in[3]; // [K, D, D]
    const float* Wm   = (const float*)d_in[4]; // [K, D, 1]
    float* out = (float*)d_out;                // [N, K] float32

    // workspace layout:
    //   [0, 3.2M)            t32      f32[N*K]
    //   [3.2M, 6.4M)         agg32    f32[N*K]
    //   [6.4M, 12.8M)        s64      f64[N*K]  (early: lists int[K][N], 3.2M)
    //   [12.8M, +100000)     flag8    u8[N]
    //   [12,900,000, +32)    cnts     int[8]
    //   [12,900,032, +4+pad) wlcnt    int
    //   [12,900,040, +2M)    wl       int2[WL_CAP]
    //   [14,997,192, +3.2M)  base32   f32[N*K]
    //   [18,197,192, +100000) mb      u8[N]      (end ~18.3 MB)
    char* w = (char*)d_ws;
    float*         t32    = (float*)w;
    float*         agg32  = (float*)(w + 3200000);
    double*        s64    = (double*)(w + 6400000);
    int*           lists  = (int*)(w + 6400000);       // overlays s64 (dead then)
    unsigned char* flag8  = (unsigned char*)(w + 12800000);
    int*           cnts   = (int*)(w + 12900000);
    int*           wlcnt  = (int*)(w + 12900032);
    int2*          wl     = (int2*)(w + 12900040);
    float*         b32    = (float*)(w + 12900040 + (size_t)WL_CAP * 8);
    unsigned char* mb     = (unsigned char*)(w + 12900040 + (size_t)WL_CAP * 8 + 3200000);

    // zero t32|agg32 and flag8|cnts|wlcnt (s64 zeroed later, after gemm)
    hipMemsetAsync(w, 0, 6400000, stream);
    hipMemsetAsync(w + 12800000, 0, 100040, stream);

    compact_kernel<<<(N_NODES + 255) / 256, 256, 0, stream>>>(mask, lists, cnts, mb);

    // grid: chunks padded to x8 so bid = c0*64 + h*8 + clo covers all (c,h)
    const int nchunks = (N_NODES + CHUNK - 1) / CHUNK;          // 782
    const int nc8 = (nchunks + 7) & ~7;                          // 784
    head_gemm_kernel<<<nc8 * K, 512, 0, stream>>>(x, Ww, Wm, lists, cnts, t32, b32);

    const long long nek = (long long)N_EDGES * K;
    scatter_kernel<<<(int)((nek + 255) / 256), 256, 0, stream>>>(ei, mb, t32, agg32);

    combine_flag_kernel<<<(N_NODES + 255) / 256, 256, 0, stream>>>(
        mb, b32, agg32, out, flag8);

    // lists dead now; zero s64 for exact re-accumulation
    hipMemsetAsync(s64, 0, 6400000, stream);

    edge_flag_kernel<<<(N_EDGES + 255) / 256, 256, 0, stream>>>(
        ei, mb, flag8, wl, wlcnt);

    repair_t_kernel<<<512, 256, 0, stream>>>(x, Ww, Wm, wl, wlcnt, s64);

    repair_combine_kernel<<<(N_NODES + 255) / 256, 256, 0, stream>>>(
        x, mb, Wm, b32, agg32, s64, flag8, out);
}